// Round 1
// baseline (46735.635 us; speedup 1.0000x reference)
//
#include <hip/hip_runtime.h>
#include <math.h>

// Fused seq2seq (encoder LSTM + additive attention + decoder LSTM + vocab head)
// Single persistent kernel, 256 blocks x 512 threads, grid barriers in software.
// Block b owns hidden indices [4b, 4b+4): its LSTM cell state c stays in LDS.

#define H   1024
#define V   32000
#define L   256
#define NB  256
#define NT  512
#define NW  (NT/64)

__device__ __forceinline__ float wsum(float v){
  #pragma unroll
  for (int off = 32; off > 0; off >>= 1) v += __shfl_down(v, off, 64);
  return v;                      // lane 0 holds the total
}
__device__ __forceinline__ float wmax(float v){
  #pragma unroll
  for (int off = 32; off > 0; off >>= 1) v = fmaxf(v, __shfl_down(v, off, 64));
  return v;
}
__device__ __forceinline__ float sigmoidf(float x){ return 1.f/(1.f+expf(-x)); }
__device__ __forceinline__ unsigned fkey(float f){  // monotonic float->uint
  unsigned u = __float_as_uint(f);
  return (u & 0x80000000u) ? ~u : (u | 0x80000000u);
}
// per-lane partial of dot(W_row[0:1024], x_lds[0:1024]); reduce with wsum()
__device__ __forceinline__ float dotp(const float* __restrict__ Wr,
                                      const float4* __restrict__ x4, int lane){
  const float4* w4 = (const float4*)Wr;
  float s = 0.f;
  #pragma unroll
  for (int u = 0; u < 4; ++u){
    float4 a = w4[lane + 64*u];
    float4 x = x4[lane + 64*u];
    s += a.x*x.x + a.y*x.y + a.z*x.z + a.w*x.w;
  }
  return s;
}

// grid barrier: monotonically increasing arrive counter + generation flag.
// Device-scope scoped atomics (cross-XCD safe); __threadfence gives acq/rel.
__device__ __forceinline__ void gbar(unsigned* cnt, unsigned* gen){
  __syncthreads();
  if (threadIdx.x == 0){
    __threadfence();
    unsigned g   = __hip_atomic_load(gen, __ATOMIC_RELAXED, __HIP_MEMORY_SCOPE_AGENT);
    unsigned old = __hip_atomic_fetch_add(cnt, 1u, __ATOMIC_ACQ_REL, __HIP_MEMORY_SCOPE_AGENT);
    if ((old & (NB-1u)) == (NB-1u)){
      __hip_atomic_fetch_add(gen, 1u, __ATOMIC_ACQ_REL, __HIP_MEMORY_SCOPE_AGENT);
    } else {
      while (__hip_atomic_load(gen, __ATOMIC_RELAXED, __HIP_MEMORY_SCOPE_AGENT) == g){
        __builtin_amdgcn_s_sleep(4);
      }
    }
    __threadfence();
  }
  __syncthreads();
}

__global__ __launch_bounds__(NT, 1) void seq2seq_fused(
    const int*   __restrict__ seq_in, const float* __restrict__ embeds,
    const float* __restrict__ eWih,   const float* __restrict__ eWhh,
    const float* __restrict__ ebih,   const float* __restrict__ ebhh,
    const float* __restrict__ dWih,   const float* __restrict__ dWhh,
    const float* __restrict__ dbih,   const float* __restrict__ dbhh,
    const float* __restrict__ outW,   const float* __restrict__ outb,
    const float* __restrict__ vvec,   const float* __restrict__ w1,
    const float* __restrict__ w2,
    float* __restrict__ out, float* __restrict__ wsf, unsigned* __restrict__ hdr)
{
  const int b = blockIdx.x, tid = threadIdx.x;
  const int w = tid >> 6, lane = tid & 63;
  const int j0 = b * 4;
  unsigned* cnt = hdr;
  unsigned* gen = hdr + 1;
  unsigned long long* winner = (unsigned long long*)(hdr + 4); // byte 16, 8-aligned

  float* g_h   = wsf;                  // double-buffered h: [2][H]
  float* g_w1h = wsf + 2048;           // [H]
  float* g_sc  = wsf + 3072;           // [L] attention scores
  float* g_ctx = wsf + 3584;           // [H]
  float* g_E   = wsf + 8192;           // [L][H] encoder outputs
  float* g_Ew2 = wsf + 8192 + 262144;  // [L][H] E @ w2^T

  __shared__ __align__(16) float sA[H];
  __shared__ __align__(16) float sB[H];
  __shared__ float s_gate[16], s_gpart[16], s_c[4];
  __shared__ float s_redA[NW], s_red4[NW][4];
  __shared__ float s_bv[NW];
  __shared__ int   s_bi[NW];
  __shared__ float s_bcast[2];

  // ---- init: h = 0, c = 0 ----
  if (tid < 4){ s_c[tid] = 0.f; g_h[j0 + tid] = 0.f; }
  gbar(cnt, gen);

  // ================= encoder: 256 steps, 1 barrier each =================
  for (int t = 0; t < L; ++t){
    const int rp = t & 1, wp = rp ^ 1;
    const int tok = seq_in[t];
    for (int i = tid; i < H; i += NT){
      sA[i] = embeds[(size_t)tok*H + i];
      sB[i] = g_h[(size_t)rp*H + i];
    }
    __syncthreads();
    const float4* x4 = (const float4*)sA;
    const float4* h4 = (const float4*)sB;
    #pragma unroll
    for (int q2 = 0; q2 < 2; ++q2){
      const int lr = w + q2*NW;                 // 16 gate rows per block
      const int r  = (lr >> 2)*H + j0 + (lr & 3);
      float s = dotp(eWih + (size_t)r*H, x4, lane)
              + dotp(eWhh + (size_t)r*H, h4, lane);
      s = wsum(s);
      if (lane == 0) s_gate[lr] = s + ebih[r] + ebhh[r];
    }
    __syncthreads();
    if (tid < 4){
      const float ig = sigmoidf(s_gate[tid]);
      const float fg = sigmoidf(s_gate[4 + tid]);
      const float gg = tanhf   (s_gate[8 + tid]);
      const float og = sigmoidf(s_gate[12 + tid]);
      const float c  = fg*s_c[tid] + ig*gg;
      const float hn = og*tanhf(c);
      s_c[tid] = c;
      g_h[(size_t)wp*H + j0 + tid] = hn;
      g_E[(size_t)t*H + j0 + tid]  = hn;
    }
    gbar(cnt, gen);
  }

  // ================= Ew2 = E @ w2^T (one shot) =================
  for (int i = w; i < L; i += NW){
    const float* Ei = g_E + (size_t)i*H;
    float4 e4[4];
    #pragma unroll
    for (int u = 0; u < 4; ++u) e4[u] = ((const float4*)Ei)[lane + 64*u];
    #pragma unroll
    for (int jj = 0; jj < 4; ++jj){
      const float4* w4 = (const float4*)(w2 + (size_t)(j0 + jj)*H);
      float s = 0.f;
      #pragma unroll
      for (int u = 0; u < 4; ++u){
        float4 a = w4[lane + 64*u];
        s += a.x*e4[u].x + a.y*e4[u].y + a.z*e4[u].z + a.w*e4[u].w;
      }
      s = wsum(s);
      if (lane == 0) g_Ew2[(size_t)i*H + j0 + jj] = s;
    }
  }
  gbar(cnt, gen);

  // ================= decoder: 256 steps, 5 barriers each =================
  for (int t = 0; t < L; ++t){
    const int rp = t & 1, wp = rp ^ 1;
    unsigned widx = 0u;
    if (t > 0){
      const unsigned long long wn = winner[wp];     // step t-1 winner
      widx = 0x7FFFFFFFu - (unsigned)(wn & 0xFFFFFFFFull);
      if (b == 0 && tid == 0) out[(size_t)L*V + (t-1)] = (float)widx;
    }
    if (b == 0 && tid == 0) winner[rp] = 0ull;      // slot for THIS step

    // ---- A: w1h = w1@h  ||  gate partials (Whh@h + Wih[:, :H]@relu(prev)) ----
    for (int i = tid; i < H; i += NT){
      sB[i] = g_h[(size_t)rp*H + i];
      float pv = (t > 0) ? embeds[(size_t)widx*H + i] : 0.f;
      sA[i] = fmaxf(pv, 0.f);                       // relu(prev embedding)
    }
    __syncthreads();
    const float4* hh4 = (const float4*)sB;
    const float4* pr4 = (const float4*)sA;
    #pragma unroll
    for (int q2 = 0; q2 < 2; ++q2){
      const int lr = w + q2*NW;
      const int r  = (lr >> 2)*H + j0 + (lr & 3);
      float s = dotp(dWhh + (size_t)r*H, hh4, lane);
      if (t > 0) s += dotp(dWih + (size_t)r*2*H, pr4, lane);
      s = wsum(s);
      if (lane == 0) s_gpart[lr] = s + dbih[r] + dbhh[r];
    }
    if (w < 4){
      const int r = j0 + w;
      float s = wsum(dotp(w1 + (size_t)r*H, hh4, lane));
      if (lane == 0) g_w1h[r] = s;
    }
    gbar(cnt, gen);

    // ---- B: score_b = v . tanh(w1h + Ew2[b]) ----
    {
      const float* ew = g_Ew2 + (size_t)b*H;
      float p = 0.f;
      for (int i = tid; i < H; i += NT) p += vvec[i]*tanhf(g_w1h[i] + ew[i]);
      p = wsum(p);
      if (lane == 0) s_redA[w] = p;
      __syncthreads();
      if (tid == 0){
        float s = 0.f;
        for (int k = 0; k < NW; ++k) s += s_redA[k];
        g_sc[b] = s;
      }
    }
    gbar(cnt, gen);

    // ---- C: softmax (redundant per block) + ctx chunk [4b,4b+4) ----
    {
      float sv = (tid < L) ? g_sc[tid] : -INFINITY;
      float mx = wmax(sv);
      if (lane == 0) s_redA[w] = mx;
      __syncthreads();
      if (tid == 0){
        float m = s_redA[0];
        for (int k = 1; k < NW; ++k) m = fmaxf(m, s_redA[k]);
        s_bcast[0] = m;
      }
      __syncthreads();
      const float m = s_bcast[0];
      float e = (tid < L) ? expf(sv - m) : 0.f;
      float ss = wsum(e);
      if (lane == 0) s_redA[w] = ss;
      __syncthreads();
      if (tid == 0){
        float s = 0.f;
        for (int k = 0; k < NW; ++k) s += s_redA[k];
        s_bcast[1] = s;
      }
      __syncthreads();
      const float a = e / s_bcast[1];
      float qx = 0, qy = 0, qz = 0, qw = 0;
      if (tid < L){
        const float4 ev = *(const float4*)(g_E + (size_t)tid*H + j0);
        qx = a*ev.x; qy = a*ev.y; qz = a*ev.z; qw = a*ev.w;
      }
      qx = wsum(qx); qy = wsum(qy); qz = wsum(qz); qw = wsum(qw);
      if (lane == 0){ s_red4[w][0]=qx; s_red4[w][1]=qy; s_red4[w][2]=qz; s_red4[w][3]=qw; }
      __syncthreads();
      if (tid < 4){
        float s = 0.f;
        for (int k = 0; k < NW; ++k) s += s_red4[k][tid];
        g_ctx[j0 + tid] = s;
      }
    }
    gbar(cnt, gen);

    // ---- D: finish gates with Wih[:, H:2H]@ctx, LSTM update ----
    for (int i = tid; i < H; i += NT) sA[i] = g_ctx[i];
    __syncthreads();
    const float4* cx4 = (const float4*)sA;
    #pragma unroll
    for (int q2 = 0; q2 < 2; ++q2){
      const int lr = w + q2*NW;
      const int r  = (lr >> 2)*H + j0 + (lr & 3);
      float s = wsum(dotp(dWih + (size_t)r*2*H + H, cx4, lane));
      if (lane == 0) s_gate[lr] = s_gpart[lr] + s;
    }
    __syncthreads();
    if (tid < 4){
      const float ig = sigmoidf(s_gate[tid]);
      const float fg = sigmoidf(s_gate[4 + tid]);
      const float gg = tanhf   (s_gate[8 + tid]);
      const float og = sigmoidf(s_gate[12 + tid]);
      const float c  = fg*s_c[tid] + ig*gg;
      const float hn = og*tanhf(c);
      s_c[tid] = c;
      g_h[(size_t)wp*H + j0 + tid] = hn;
    }
    gbar(cnt, gen);

    // ---- E: logits = outW@h2 + outb, write preds, block argmax -> atomicMax ----
    for (int i = tid; i < H; i += NT) sB[i] = g_h[(size_t)wp*H + i];
    __syncthreads();
    {
      const float4* h4b = (const float4*)sB;
      float bv = -INFINITY; int bi = 0x7FFFFFFF;
      const int r0 = b * 125;                        // 32000 = 256*125
      for (int g4 = 0; g4 < 4; ++g4){                // 4 rows in flight per wave
        const int k0 = w*16 + g4*4;
        int rr[4];
        #pragma unroll
        for (int u = 0; u < 4; ++u) rr[u] = r0 + min(k0 + u, 124); // clamp dups
        const float4* W0 = (const float4*)(outW + (size_t)rr[0]*H);
        const float4* W1 = (const float4*)(outW + (size_t)rr[1]*H);
        const float4* W2 = (const float4*)(outW + (size_t)rr[2]*H);
        const float4* W3 = (const float4*)(outW + (size_t)rr[3]*H);
        float s0=0, s1=0, s2=0, s3=0;
        #pragma unroll
        for (int u = 0; u < 4; ++u){
          const float4 hb = h4b[lane + 64*u];
          float4 a0 = W0[lane+64*u]; s0 += a0.x*hb.x+a0.y*hb.y+a0.z*hb.z+a0.w*hb.w;
          float4 a1 = W1[lane+64*u]; s1 += a1.x*hb.x+a1.y*hb.y+a1.z*hb.z+a1.w*hb.w;
          float4 a2 = W2[lane+64*u]; s2 += a2.x*hb.x+a2.y*hb.y+a2.z*hb.z+a2.w*hb.w;
          float4 a3 = W3[lane+64*u]; s3 += a3.x*hb.x+a3.y*hb.y+a3.z*hb.z+a3.w*hb.w;
        }
        s0 = wsum(s0); s1 = wsum(s1); s2 = wsum(s2); s3 = wsum(s3);
        if (lane == 0){
          float dv[4] = {s0, s1, s2, s3};
          #pragma unroll
          for (int u = 0; u < 4; ++u){
            const int r = rr[u];
            const float dd = dv[u] + outb[r];
            out[(size_t)t*V + r] = dd;
            if (dd > bv || (dd == bv && r < bi)){ bv = dd; bi = r; }
          }
        }
      }
      if (lane == 0){ s_bv[w] = bv; s_bi[w] = bi; }
      __syncthreads();
      if (tid == 0){
        float v0 = -INFINITY; int i0 = 0x7FFFFFFF;
        for (int k = 0; k < NW; ++k){
          const float vv = s_bv[k]; const int ii = s_bi[k];
          if (vv > v0 || (vv == v0 && ii < i0)){ v0 = vv; i0 = ii; }
        }
        const unsigned long long pk =
            ((unsigned long long)fkey(v0) << 32) |
            (unsigned long long)(0x7FFFFFFFu - (unsigned)i0);  // low idx wins ties
        atomicMax(winner + rp, pk);
      }
    }
    gbar(cnt, gen);
  }

  if (b == 0 && tid == 0){
    const unsigned long long wn = winner[(L-1) & 1];
    out[(size_t)L*V + (L-1)] = (float)(0x7FFFFFFFu - (unsigned)(wn & 0xFFFFFFFFull));
  }
}

extern "C" void kernel_launch(void* const* d_in, const int* in_sizes, int n_in,
                              void* d_out, int out_size, void* d_ws, size_t ws_size,
                              hipStream_t stream) {
  (void)in_sizes; (void)n_in; (void)out_size; (void)ws_size;
  // zero barrier counters + argmax slots (d_ws is re-poisoned before each launch)
  hipMemsetAsync(d_ws, 0, 256, stream);
  seq2seq_fused<<<dim3(NB), dim3(NT), 0, stream>>>(
      (const int*)d_in[0],  (const float*)d_in[1],
      (const float*)d_in[2], (const float*)d_in[3],
      (const float*)d_in[4], (const float*)d_in[5],
      (const float*)d_in[6], (const float*)d_in[7],
      (const float*)d_in[8], (const float*)d_in[9],
      (const float*)d_in[10], (const float*)d_in[11],
      (const float*)d_in[12], (const float*)d_in[13],
      (const float*)d_in[14],
      (float*)d_out, (float*)((char*)d_ws + 128), (unsigned*)d_ws);
}

// Round 2
// 14569.440 us; speedup vs baseline: 3.2078x; 3.2078x over previous
//
#include <hip/hip_runtime.h>
#include <math.h>

// Fused seq2seq: encoder LSTM + additive attention + decoder LSTM + vocab head.
// 256 blocks x 512 threads, fully fence-free: all cross-block communication is
// via tagged relaxed agent-scope 64-bit atomics ((tag<<32)|f32bits). No grid
// barrier / no __threadfence -> no buffer_wbl2/buffer_inv -> L2 stays warm.
// Block b owns hidden indices [4b,4b+4); E[:,4b:4b+4] and Ew2[b,:] live in LDS.

#define H   1024
#define V   32000
#define L   256
#define NB  256
#define NT  512
#define NW  (NT/64)

typedef unsigned long long u64;

__device__ __forceinline__ float wsum(float v){
  #pragma unroll
  for (int off = 32; off > 0; off >>= 1) v += __shfl_down(v, off, 64);
  return v;                      // lane 0 holds the total
}
__device__ __forceinline__ float wmaxf(float v){
  #pragma unroll
  for (int off = 32; off > 0; off >>= 1) v = fmaxf(v, __shfl_down(v, off, 64));
  return v;
}
__device__ __forceinline__ u64 wmaxu(u64 v){
  #pragma unroll
  for (int off = 32; off > 0; off >>= 1){
    u64 o = __shfl_down(v, off, 64);
    if (o > v) v = o;
  }
  return v;
}
__device__ __forceinline__ float sigmoidf(float x){ return 1.f/(1.f+expf(-x)); }
__device__ __forceinline__ unsigned fkey(float f){  // monotonic float->uint
  unsigned u = __float_as_uint(f);
  return (u & 0x80000000u) ? ~u : (u | 0x80000000u);
}
// per-lane partial of dot(W_row[0:1024], x_lds[0:1024]); reduce with wsum()
__device__ __forceinline__ float dotp(const float* __restrict__ Wr,
                                      const float4* __restrict__ x4, int lane){
  const float4* w4 = (const float4*)Wr;
  float s = 0.f;
  #pragma unroll
  for (int u = 0; u < 4; ++u){
    float4 a = w4[lane + 64*u];
    float4 x = x4[lane + 64*u];
    s += a.x*x.x + a.y*x.y + a.z*x.z + a.w*x.w;
  }
  return s;
}

// ---------- tagged relaxed-atomic channels (fence-free cross-XCD sync) ----------
// Safety: channel buffer p holding tag T is only overwritten with tag T+2; the
// phase-dependency chain guarantees every block has consumed tag T by then.
__device__ __forceinline__ void pub(u64* ch, int idx, unsigned tag, float f){
  u64 v = ((u64)tag << 32) | (u64)__float_as_uint(f);
  __hip_atomic_store(ch + idx, v, __ATOMIC_RELAXED, __HIP_MEMORY_SCOPE_AGENT);
}
__device__ __forceinline__ float spin1(u64* p, unsigned tag){
  u64 v = __hip_atomic_load(p, __ATOMIC_RELAXED, __HIP_MEMORY_SCOPE_AGENT);
  while ((unsigned)(v >> 32) != tag){
    __builtin_amdgcn_s_sleep(2);
    v = __hip_atomic_load(p, __ATOMIC_RELAXED, __HIP_MEMORY_SCOPE_AGENT);
  }
  return __uint_as_float((unsigned)v);
}
// read a 1024-float channel (2 elements/thread); both loads issued before waiting
__device__ __forceinline__ void ch_read(u64* ch, unsigned tag, float* dst, int tid){
  u64 v0 = __hip_atomic_load(ch + tid,      __ATOMIC_RELAXED, __HIP_MEMORY_SCOPE_AGENT);
  u64 v1 = __hip_atomic_load(ch + tid + NT, __ATOMIC_RELAXED, __HIP_MEMORY_SCOPE_AGENT);
  while ((unsigned)(v0 >> 32) != tag){
    __builtin_amdgcn_s_sleep(2);
    v0 = __hip_atomic_load(ch + tid, __ATOMIC_RELAXED, __HIP_MEMORY_SCOPE_AGENT);
  }
  while ((unsigned)(v1 >> 32) != tag){
    __builtin_amdgcn_s_sleep(2);
    v1 = __hip_atomic_load(ch + tid + NT, __ATOMIC_RELAXED, __HIP_MEMORY_SCOPE_AGENT);
  }
  dst[tid]      = __uint_as_float((unsigned)v0);
  dst[tid + NT] = __uint_as_float((unsigned)v1);
}
// winner slot format: [tag:17][fkey(val):32][0x7FFF-idx:15]  (max => argmax, low idx ties)
__device__ __forceinline__ unsigned win_reduce(u64* slot, unsigned tag,
                                               u64* s_k, unsigned* s_w,
                                               int tid, int w, int lane){
  u64 key = 0ull;
  if (tid < NB){
    u64* p = slot + tid;
    u64 v = __hip_atomic_load(p, __ATOMIC_RELAXED, __HIP_MEMORY_SCOPE_AGENT);
    while ((unsigned)(v >> 47) != tag){
      __builtin_amdgcn_s_sleep(2);
      v = __hip_atomic_load(p, __ATOMIC_RELAXED, __HIP_MEMORY_SCOPE_AGENT);
    }
    key = v & 0x7FFFFFFFFFFFull;
  }
  key = wmaxu(key);
  if (lane == 0) s_k[w] = key;
  __syncthreads();
  if (tid == 0){
    u64 m = s_k[0];
    for (int k = 1; k < NW; ++k) if (s_k[k] > m) m = s_k[k];
    *s_w = 0x7FFFu - (unsigned)(m & 0x7FFFull);
  }
  __syncthreads();
  return *s_w;
}

__global__ __launch_bounds__(NT, 1) void seq2seq_fused(
    const int*   __restrict__ seq_in, const float* __restrict__ embeds,
    const float* __restrict__ eWih,   const float* __restrict__ eWhh,
    const float* __restrict__ ebih,   const float* __restrict__ ebhh,
    const float* __restrict__ dWih,   const float* __restrict__ dWhh,
    const float* __restrict__ dbih,   const float* __restrict__ dbhh,
    const float* __restrict__ outW,   const float* __restrict__ outb,
    const float* __restrict__ vvec,   const float* __restrict__ w1,
    const float* __restrict__ w2,
    float* __restrict__ out, u64* __restrict__ ws)
{
  const int b = blockIdx.x, tid = threadIdx.x;
  const int w = tid >> 6, lane = tid & 63;
  const int j0 = b * 4;

  u64* chH  = ws;                    // [2][H]  encoder h stream
  u64* chW1 = ws + 2*H;              // [2][H]  w1 @ h
  u64* chSc = ws + 4*H;              // [2][NB] attention scores
  u64* chCx = ws + 4*H + 2*NB;       // [2][H]  context
  u64* chH2 = ws + 6*H + 2*NB;       // [2][H]  decoder h stream
  u64* chWin= ws + 8*H + 2*NB;       // [2][NB] per-block argmax keys

  __shared__ __align__(16) float sA[H];
  __shared__ __align__(16) float sB[H];
  __shared__ __align__(16) float sMyE[H];       // E[b, :]
  __shared__ __align__(16) float sEw2[H];       // Ew2[b, :]
  __shared__ __align__(16) float sEcol[L*4];    // E[:, 4b:4b+4]
  __shared__ float s_gate[16], s_gpart[16], s_c[4];
  __shared__ float s_redA[NW], s_red4[NW][4];
  __shared__ float s_bv[NW];
  __shared__ int   s_bi[NW];
  __shared__ float s_bcast[2];
  __shared__ u64   s_k[NW];
  __shared__ unsigned s_widx;

  if (tid < 4) s_c[tid] = 0.f;

  // ================= encoder: dataflow-synced, 1 channel hop/step =================
  for (int t = 0; t < L; ++t){
    if (t == 0){
      for (int i = tid; i < H; i += NT) sB[i] = 0.f;
    } else {
      ch_read(chH + (t & 1)*H, (unsigned)t, sB, tid);
    }
    if (t == b + 1){ sMyE[tid] = sB[tid]; sMyE[tid + NT] = sB[tid + NT]; } // E row b
    const int tok = seq_in[t];
    for (int i = tid; i < H; i += NT) sA[i] = embeds[(size_t)tok*H + i];
    __syncthreads();
    const float4* x4 = (const float4*)sA;
    const float4* h4 = (const float4*)sB;
    #pragma unroll
    for (int q2 = 0; q2 < 2; ++q2){
      const int lr = w + q2*NW;                 // 16 gate rows per block
      const int r  = (lr >> 2)*H + j0 + (lr & 3);
      float s = dotp(eWih + (size_t)r*H, x4, lane)
              + dotp(eWhh + (size_t)r*H, h4, lane);
      s = wsum(s);
      if (lane == 0) s_gate[lr] = s + ebih[r] + ebhh[r];
    }
    __syncthreads();
    if (tid < 4){
      const float ig = sigmoidf(s_gate[tid]);
      const float fg = sigmoidf(s_gate[4 + tid]);
      const float gg = tanhf   (s_gate[8 + tid]);
      const float og = sigmoidf(s_gate[12 + tid]);
      const float c  = fg*s_c[tid] + ig*gg;
      const float hn = og*tanhf(c);
      s_c[tid] = c;
      sEcol[t*4 + tid] = hn;                    // E column slice stays in LDS
      pub(chH + ((t+1) & 1)*H, j0 + tid, (unsigned)(t+1), hn);
    }
  }
  if (b == L-1) ch_read(chH + ((L & 1))*H, (unsigned)L, sMyE, tid); // last E row
  __syncthreads();

  // ================= Ew2[b,:] = dot(E[b,:], w2[j,:]) — block-local =================
  {
    const float4* e4p = (const float4*)sMyE;
    for (int g4 = 0; g4 < 32; ++g4){
      const int jr = w*128 + g4*4;
      const float4* W0 = (const float4*)(w2 + (size_t)(jr+0)*H);
      const float4* W1 = (const float4*)(w2 + (size_t)(jr+1)*H);
      const float4* W2 = (const float4*)(w2 + (size_t)(jr+2)*H);
      const float4* W3 = (const float4*)(w2 + (size_t)(jr+3)*H);
      float s0=0, s1=0, s2=0, s3=0;
      #pragma unroll
      for (int u = 0; u < 4; ++u){
        const float4 e = e4p[lane + 64*u];
        float4 a0 = W0[lane+64*u]; s0 += a0.x*e.x+a0.y*e.y+a0.z*e.z+a0.w*e.w;
        float4 a1 = W1[lane+64*u]; s1 += a1.x*e.x+a1.y*e.y+a1.z*e.z+a1.w*e.w;
        float4 a2 = W2[lane+64*u]; s2 += a2.x*e.x+a2.y*e.y+a2.z*e.z+a2.w*e.w;
        float4 a3 = W3[lane+64*u]; s3 += a3.x*e.x+a3.y*e.y+a3.z*e.z+a3.w*e.w;
      }
      s0 = wsum(s0); s1 = wsum(s1); s2 = wsum(s2); s3 = wsum(s3);
      if (lane == 0){ sEw2[jr]=s0; sEw2[jr+1]=s1; sEw2[jr+2]=s2; sEw2[jr+3]=s3; }
    }
  }
  __syncthreads();

  // ================= decoder: 5 dataflow hops/step, no barriers =================
  for (int t = 0; t < L; ++t){
    // ---- A: winner(t-1), h, prev-embed; w1h + gate partials ----
    unsigned widx = 0u;
    if (t > 0){
      widx = win_reduce(chWin + ((t-1) & 1)*NB, (unsigned)t, s_k, &s_widx, tid, w, lane);
      if (b == 0 && tid == 0) out[(size_t)L*V + (t-1)] = (float)widx;
    }
    if (t == 0) ch_read(chH  + ((L & 1))*H, (unsigned)L, sB, tid);
    else        ch_read(chH2 + (t & 1)*H,   (unsigned)t, sB, tid);
    for (int i = tid; i < H; i += NT){
      float pv = (t > 0) ? embeds[(size_t)widx*H + i] : 0.f;
      sA[i] = fmaxf(pv, 0.f);                   // relu(prev embedding)
    }
    __syncthreads();
    const float4* hh4 = (const float4*)sB;
    const float4* pr4 = (const float4*)sA;
    #pragma unroll
    for (int q2 = 0; q2 < 2; ++q2){
      const int lr = w + q2*NW;
      const int r  = (lr >> 2)*H + j0 + (lr & 3);
      float s = dotp(dWhh + (size_t)r*H, hh4, lane);
      if (t > 0) s += dotp(dWih + (size_t)r*2*H, pr4, lane);
      s = wsum(s);
      if (lane == 0) s_gpart[lr] = s + dbih[r] + dbhh[r];
    }
    if (w < 4){
      const int r = j0 + w;
      float s = wsum(dotp(w1 + (size_t)r*H, hh4, lane));
      if (lane == 0) pub(chW1 + (t & 1)*H, r, (unsigned)(t+1), s);
    }

    // ---- B: score_b = v . tanh(w1h + Ew2[b]) ----
    __syncthreads();                            // protect sA overwrite vs A dots
    ch_read(chW1 + (t & 1)*H, (unsigned)(t+1), sA, tid);
    __syncthreads();
    {
      float p = 0.f;
      for (int i = tid; i < H; i += NT) p += vvec[i]*tanhf(sA[i] + sEw2[i]);
      p = wsum(p);
      if (lane == 0) s_redA[w] = p;
      __syncthreads();
      if (tid == 0){
        float s = 0.f;
        for (int k = 0; k < NW; ++k) s += s_redA[k];
        pub(chSc + (t & 1)*NB, b, (unsigned)(t+1), s);
      }
    }

    // ---- C: softmax (redundant per block) + ctx chunk [4b,4b+4) ----
    __syncthreads();
    {
      float sv = -INFINITY;
      if (tid < L) sv = spin1(chSc + (t & 1)*NB + tid, (unsigned)(t+1));
      float mx = wmaxf(sv);
      if (lane == 0) s_redA[w] = mx;
      __syncthreads();
      if (tid == 0){
        float m = s_redA[0];
        for (int k = 1; k < NW; ++k) m = fmaxf(m, s_redA[k]);
        s_bcast[0] = m;
      }
      __syncthreads();
      const float m = s_bcast[0];
      float e = (tid < L) ? expf(sv - m) : 0.f;
      float ss = wsum(e);
      if (lane == 0) s_redA[w] = ss;
      __syncthreads();
      if (tid == 0){
        float s = 0.f;
        for (int k = 0; k < NW; ++k) s += s_redA[k];
        s_bcast[1] = s;
      }
      __syncthreads();
      const float a = e / s_bcast[1];
      float qx = 0, qy = 0, qz = 0, qw = 0;
      if (tid < L){
        const float4 ev = *(const float4*)(sEcol + tid*4);
        qx = a*ev.x; qy = a*ev.y; qz = a*ev.z; qw = a*ev.w;
      }
      qx = wsum(qx); qy = wsum(qy); qz = wsum(qz); qw = wsum(qw);
      if (lane == 0){ s_red4[w][0]=qx; s_red4[w][1]=qy; s_red4[w][2]=qz; s_red4[w][3]=qw; }
      __syncthreads();
      if (tid < 4){
        float s = 0.f;
        for (int k = 0; k < NW; ++k) s += s_red4[k][tid];
        pub(chCx + (t & 1)*H, j0 + tid, (unsigned)(t+1), s);
      }
    }

    // ---- D: finish gates with Wih[:, H:2H]@ctx, LSTM update ----
    ch_read(chCx + (t & 1)*H, (unsigned)(t+1), sA, tid);
    __syncthreads();
    const float4* cx4 = (const float4*)sA;
    #pragma unroll
    for (int q2 = 0; q2 < 2; ++q2){
      const int lr = w + q2*NW;
      const int r  = (lr >> 2)*H + j0 + (lr & 3);
      float s = wsum(dotp(dWih + (size_t)r*2*H + H, cx4, lane));
      if (lane == 0) s_gate[lr] = s_gpart[lr] + s;
    }
    __syncthreads();
    if (tid < 4){
      const float ig = sigmoidf(s_gate[tid]);
      const float fg = sigmoidf(s_gate[4 + tid]);
      const float gg = tanhf   (s_gate[8 + tid]);
      const float og = sigmoidf(s_gate[12 + tid]);
      const float c  = fg*s_c[tid] + ig*gg;
      const float hn = og*tanhf(c);
      s_c[tid] = c;
      pub(chH2 + ((t+1) & 1)*H, j0 + tid, (unsigned)(t+1), hn);
    }

    // ---- E: logits = outW@h2 + outb, write preds, block argmax -> channel ----
    ch_read(chH2 + ((t+1) & 1)*H, (unsigned)(t+1), sB, tid);
    __syncthreads();
    {
      const float4* h4b = (const float4*)sB;
      float bv = -INFINITY; int bi = 0x7FFFFFFF;
      const int r0 = b * 125;                    // 32000 = 256*125
      for (int g4 = 0; g4 < 4; ++g4){            // 4 rows in flight per wave
        const int k0 = w*16 + g4*4;
        int rr[4];
        #pragma unroll
        for (int u = 0; u < 4; ++u) rr[u] = r0 + min(k0 + u, 124); // clamp dups
        const float4* W0 = (const float4*)(outW + (size_t)rr[0]*H);
        const float4* W1 = (const float4*)(outW + (size_t)rr[1]*H);
        const float4* W2 = (const float4*)(outW + (size_t)rr[2]*H);
        const float4* W3 = (const float4*)(outW + (size_t)rr[3]*H);
        float s0=0, s1=0, s2=0, s3=0;
        #pragma unroll
        for (int u = 0; u < 4; ++u){
          const float4 hb = h4b[lane + 64*u];
          float4 a0 = W0[lane+64*u]; s0 += a0.x*hb.x+a0.y*hb.y+a0.z*hb.z+a0.w*hb.w;
          float4 a1 = W1[lane+64*u]; s1 += a1.x*hb.x+a1.y*hb.y+a1.z*hb.z+a1.w*hb.w;
          float4 a2 = W2[lane+64*u]; s2 += a2.x*hb.x+a2.y*hb.y+a2.z*hb.z+a2.w*hb.w;
          float4 a3 = W3[lane+64*u]; s3 += a3.x*hb.x+a3.y*hb.y+a3.z*hb.z+a3.w*hb.w;
        }
        s0 = wsum(s0); s1 = wsum(s1); s2 = wsum(s2); s3 = wsum(s3);
        if (lane == 0){
          float dv[4] = {s0, s1, s2, s3};
          #pragma unroll
          for (int u = 0; u < 4; ++u){
            const int r = rr[u];
            const float dd = dv[u] + outb[r];
            out[(size_t)t*V + r] = dd;
            if (dd > bv || (dd == bv && r < bi)){ bv = dd; bi = r; }
          }
        }
      }
      if (lane == 0){ s_bv[w] = bv; s_bi[w] = bi; }
      __syncthreads();
      if (tid == 0){
        float v0 = -INFINITY; int i0 = 0x7FFFFFFF;
        for (int k = 0; k < NW; ++k){
          const float vv = s_bv[k]; const int ii = s_bi[k];
          if (vv > v0 || (vv == v0 && ii < i0)){ v0 = vv; i0 = ii; }
        }
        const u64 pk = ((u64)(unsigned)(t+1) << 47)
                     | ((u64)fkey(v0) << 15)
                     | (u64)(0x7FFFu - (unsigned)i0);
        __hip_atomic_store(chWin + (t & 1)*NB + b, pk,
                           __ATOMIC_RELAXED, __HIP_MEMORY_SCOPE_AGENT);
      }
    }
  }

  if (b == 0){
    unsigned widx = win_reduce(chWin + ((L-1) & 1)*NB, (unsigned)L, s_k, &s_widx, tid, w, lane);
    if (tid == 0) out[(size_t)L*V + (L-1)] = (float)widx;
  }
}

extern "C" void kernel_launch(void* const* d_in, const int* in_sizes, int n_in,
                              void* d_out, int out_size, void* d_ws, size_t ws_size,
                              hipStream_t stream) {
  (void)in_sizes; (void)n_in; (void)out_size; (void)ws_size;
  // No memset needed: channel tags (1..256) never match the 0xAA poison pattern.
  seq2seq_fused<<<dim3(NB), dim3(NT), 0, stream>>>(
      (const int*)d_in[0],  (const float*)d_in[1],
      (const float*)d_in[2], (const float*)d_in[3],
      (const float*)d_in[4], (const float*)d_in[5],
      (const float*)d_in[6], (const float*)d_in[7],
      (const float*)d_in[8], (const float*)d_in[9],
      (const float*)d_in[10], (const float*)d_in[11],
      (const float*)d_in[12], (const float*)d_in[13],
      (const float*)d_in[14],
      (float*)d_out, (u64*)d_ws);
}